// Round 1
// baseline (689.862 us; speedup 1.0000x reference)
//
#include <hip/hip_runtime.h>

#define BATCH 2048
#define IN_SZ 40960
#define HID 256
#define MAXF 48   // ACTIVE=30 max nonzeros per row; margin

// ---------------------------------------------------------------------------
// Transpose ft_w [HID][IN_SZ] -> ftT [IN_SZ][HID] so per-feature gathers are
// contiguous 1KB rows. Standard 32x32 LDS tile, padded to kill bank conflicts.
// ---------------------------------------------------------------------------
__global__ __launch_bounds__(256) void ft_transpose(const float* __restrict__ ftw,
                                                    float* __restrict__ ftT) {
    __shared__ float tile[32][33];
    const int tx = threadIdx.x;   // 0..31
    const int ty = threadIdx.y;   // 0..7
    const int bx = blockIdx.x;    // IN_SZ/32 = 1280
    const int by = blockIdx.y;    // HID/32  = 8

    const int col = bx * 32 + tx;               // IN index (coalesced read)
#pragma unroll
    for (int j = 0; j < 32; j += 8) {
        const int row = by * 32 + ty + j;       // HID index
        tile[ty + j][tx] = ftw[(size_t)row * IN_SZ + col];
    }
    __syncthreads();

    const int ocol = by * 32 + tx;              // HID index (coalesced write)
#pragma unroll
    for (int j = 0; j < 32; j += 8) {
        const int orow = bx * 32 + ty + j;      // IN index
        ftT[(size_t)orow * HID + ocol] = tile[tx][ty + j];
    }
}

// ---------------------------------------------------------------------------
// One block per batch row. Phases:
//  1) float4 scan of white/black one-hot rows -> LDS active-index lists
//  2) per-thread-h accumulate ft columns (coalesced rows of ftT), clip
//  3) stm-ordered concat -> LDS hidden[512]
//  4) l1 (512->32): 8 lanes per output, shuffle reduce; clip
//  5) l2 (32->32) on lanes 0..31; l3 (32->1) serial on lane 0
// ---------------------------------------------------------------------------
template <bool TRANSPOSED>
__global__ __launch_bounds__(256) void nnue_fused(
    const float* __restrict__ wo, const float* __restrict__ bo,
    const float* __restrict__ stm,
    const float* __restrict__ ftw,   // TRANSPOSED ? [IN_SZ][HID] : [HID][IN_SZ]
    const float* __restrict__ ftb,
    const float* __restrict__ l1w, const float* __restrict__ l1b,
    const float* __restrict__ l2w, const float* __restrict__ l2b,
    const float* __restrict__ l3w, const float* __restrict__ l3b,
    float* __restrict__ out) {
    __shared__ int   idxw[MAXF], idxb[MAXF];
    __shared__ int   cntw, cntb;
    __shared__ float hidden[2 * HID];
    __shared__ float x1[32], x2[32];

    const int b = blockIdx.x;
    const int t = threadIdx.x;

    if (t == 0) { cntw = 0; cntb = 0; }
    __syncthreads();

    // ---- phase 1: scan (the HBM-bound bulk: 2 x 160KB per block) ----
    const float4* wrow = (const float4*)(wo + (size_t)b * IN_SZ);
    const float4* brow = (const float4*)(bo + (size_t)b * IN_SZ);
    for (int i = t; i < IN_SZ / 4; i += 256) {
        float4 v = wrow[i];
        float4 u = brow[i];
        if (v.x != 0.f) { int p = atomicAdd(&cntw, 1); idxw[p] = 4 * i + 0; }
        if (v.y != 0.f) { int p = atomicAdd(&cntw, 1); idxw[p] = 4 * i + 1; }
        if (v.z != 0.f) { int p = atomicAdd(&cntw, 1); idxw[p] = 4 * i + 2; }
        if (v.w != 0.f) { int p = atomicAdd(&cntw, 1); idxw[p] = 4 * i + 3; }
        if (u.x != 0.f) { int p = atomicAdd(&cntb, 1); idxb[p] = 4 * i + 0; }
        if (u.y != 0.f) { int p = atomicAdd(&cntb, 1); idxb[p] = 4 * i + 1; }
        if (u.z != 0.f) { int p = atomicAdd(&cntb, 1); idxb[p] = 4 * i + 2; }
        if (u.w != 0.f) { int p = atomicAdd(&cntb, 1); idxb[p] = 4 * i + 3; }
    }
    __syncthreads();

    // ---- phase 2: feature-transformer accumulate ----
    const int h = t;                       // 0..255 == HID
    float accw = ftb[h];
    float accb = accw;
    const int cw = cntw, cb = cntb;
    for (int j = 0; j < cw; ++j) {
        const int f = idxw[j];
        accw += TRANSPOSED ? ftw[(size_t)f * HID + h] : ftw[(size_t)h * IN_SZ + f];
    }
    for (int j = 0; j < cb; ++j) {
        const int f = idxb[j];
        accb += TRANSPOSED ? ftw[(size_t)f * HID + h] : ftw[(size_t)h * IN_SZ + f];
    }
    accw = fminf(fmaxf(accw, 0.f), 1.f);
    accb = fminf(fmaxf(accb, 0.f), 1.f);

    // ---- phase 3: stm-ordered concat ----
    const bool s = (stm[b] != 0.f);
    hidden[h]       = s ? accw : accb;
    hidden[HID + h] = s ? accb : accw;
    __syncthreads();

    // ---- phase 4: l1 (512 -> 32), 8 lanes per output ----
    {
        const int o = t >> 3;              // 0..31
        const int part = t & 7;            // 0..7
        const float* w1 = l1w + o * (2 * HID);
        float sum = 0.f;
#pragma unroll 8
        for (int i = part; i < 2 * HID; i += 8)
            sum += hidden[i] * w1[i];
        sum += __shfl_xor(sum, 1);
        sum += __shfl_xor(sum, 2);
        sum += __shfl_xor(sum, 4);
        if (part == 0) x1[o] = fminf(fmaxf(sum + l1b[o], 0.f), 1.f);
    }
    __syncthreads();

    // ---- phase 5: l2 (32 -> 32) ----
    if (t < 32) {
        const float* w2 = l2w + t * 32;
        float sum = l2b[t];
#pragma unroll
        for (int i = 0; i < 32; ++i) sum += x1[i] * w2[i];
        x2[t] = fminf(fmaxf(sum, 0.f), 1.f);
    }
    __syncthreads();

    // ---- l3 (32 -> 1) ----
    if (t == 0) {
        float sum = l3b[0];
#pragma unroll
        for (int i = 0; i < 32; ++i) sum += x2[i] * l3w[i];
        out[b] = sum;
    }
}

extern "C" void kernel_launch(void* const* d_in, const int* in_sizes, int n_in,
                              void* d_out, int out_size, void* d_ws, size_t ws_size,
                              hipStream_t stream) {
    const float* wo  = (const float*)d_in[0];
    const float* bo  = (const float*)d_in[1];
    const float* stm = (const float*)d_in[2];
    const float* ftw = (const float*)d_in[3];
    const float* ftb = (const float*)d_in[4];
    const float* l1w = (const float*)d_in[5];
    const float* l1b = (const float*)d_in[6];
    const float* l2w = (const float*)d_in[7];
    const float* l2b = (const float*)d_in[8];
    const float* l3w = (const float*)d_in[9];
    const float* l3b = (const float*)d_in[10];
    float* out = (float*)d_out;

    const size_t need = (size_t)IN_SZ * HID * sizeof(float);
    if (ws_size >= need) {
        float* ftT = (float*)d_ws;
        ft_transpose<<<dim3(IN_SZ / 32, HID / 32), dim3(32, 8), 0, stream>>>(ftw, ftT);
        nnue_fused<true><<<BATCH, 256, 0, stream>>>(wo, bo, stm, ftT, ftb,
                                                    l1w, l1b, l2w, l2b, l3w, l3b, out);
    } else {
        // fallback: strided ft_w column gather (slower but correct)
        nnue_fused<false><<<BATCH, 256, 0, stream>>>(wo, bo, stm, ftw, ftb,
                                                     l1w, l1b, l2w, l2b, l3w, l3b, out);
    }
}